// Round 5
// baseline (1019.183 us; speedup 1.0000x reference)
//
#include <hip/hip_runtime.h>
#include <cstddef>

__device__ __forceinline__ unsigned f2mono(float f){
  unsigned u = __float_as_uint(f);
  return (u & 0x80000000u) ? ~u : (u | 0x80000000u);
}
__device__ __forceinline__ float mono2f(unsigned u){
  return (u & 0x80000000u) ? __uint_as_float(u & 0x7fffffffu) : __uint_as_float(~u);
}

// ---------------- weight transpose: Wt[k][j] = W[j][k], 128x128 f32 ------------
struct WPtrs { const float* w[8]; };
__global__ void k_transpose_all(WPtrs p, float* __restrict__ WT){
  int wi = blockIdx.y;
  const float* W = p.w[wi];
  float* Wt = WT + (size_t)wi * 16384;
  int j = blockIdx.x, k = threadIdx.x;
  Wt[k*128 + j] = W[j*128 + k];
}

// ---------------- GEMM 128: out[r][j] = act(sum_k in[r][k]*W[j][k] + b[j]) (+res)
template<int ACT>   // ACT: 0 none, 1 relu
__global__ __launch_bounds__(256) void k_gemm128(
    const float* __restrict__ in, const float* __restrict__ Wt,
    const float* __restrict__ bias, const float* __restrict__ res,
    float* __restrict__ out, int n)
{
  __shared__ float in_s[32][132];
  const int tid = threadIdx.x;
  const int r0 = blockIdx.x * 32;
  {
    int r = tid >> 3, kk = (tid & 7) * 16;
    int gr = r0 + r;
    float4* dst = (float4*)&in_s[r][kk];
    if (gr < n){
      const float4* q = (const float4*)(in + (size_t)gr*128 + kk);
#pragma unroll
      for (int w = 0; w < 4; w++) dst[w] = q[w];
    } else {
#pragma unroll
      for (int w = 0; w < 4; w++) dst[w] = make_float4(0.f,0.f,0.f,0.f);
    }
  }
  __syncthreads();
  const int rg = tid >> 5, cg = tid & 31, j0 = cg*4;
  float acc[4][4] = {};
  for (int k = 0; k < 128; k += 4){
    float4 w0 = *(const float4*)(Wt + (size_t)(k+0)*128 + j0);
    float4 w1 = *(const float4*)(Wt + (size_t)(k+1)*128 + j0);
    float4 w2 = *(const float4*)(Wt + (size_t)(k+2)*128 + j0);
    float4 w3 = *(const float4*)(Wt + (size_t)(k+3)*128 + j0);
#pragma unroll
    for (int i = 0; i < 4; i++){
      float4 a = *(const float4*)&in_s[rg*4+i][k];
      acc[i][0] += a.x*w0.x; acc[i][1] += a.x*w0.y; acc[i][2] += a.x*w0.z; acc[i][3] += a.x*w0.w;
      acc[i][0] += a.y*w1.x; acc[i][1] += a.y*w1.y; acc[i][2] += a.y*w1.z; acc[i][3] += a.y*w1.w;
      acc[i][0] += a.z*w2.x; acc[i][1] += a.z*w2.y; acc[i][2] += a.z*w2.z; acc[i][3] += a.z*w2.w;
      acc[i][0] += a.w*w3.x; acc[i][1] += a.w*w3.y; acc[i][2] += a.w*w3.z; acc[i][3] += a.w*w3.w;
    }
  }
  float bv[4] = {0.f,0.f,0.f,0.f};
  if (bias){ bv[0]=bias[j0]; bv[1]=bias[j0+1]; bv[2]=bias[j0+2]; bv[3]=bias[j0+3]; }
#pragma unroll
  for (int i = 0; i < 4; i++){
    int gr = r0 + rg*4 + i;
    if (gr >= n) continue;
    float4 o;
    o.x = acc[i][0]+bv[0]; o.y = acc[i][1]+bv[1]; o.z = acc[i][2]+bv[2]; o.w = acc[i][3]+bv[3];
    if (ACT == 1){ o.x=fmaxf(o.x,0.f); o.y=fmaxf(o.y,0.f); o.z=fmaxf(o.z,0.f); o.w=fmaxf(o.w,0.f); }
    if (res){
      float4 rv = *(const float4*)(res + (size_t)gr*128 + j0);
      o.x+=rv.x; o.y+=rv.y; o.z+=rv.z; o.w+=rv.w;
    }
    *(float4*)(out + (size_t)gr*128 + j0) = o;
  }
}

// ---------------- attention logits prep ----------------------------------------
__global__ void k_prep8(const float* __restrict__ xp, const float* __restrict__ As,
                        const float* __restrict__ Ad, float* __restrict__ es,
                        float* __restrict__ ed, int N){
  int t = blockIdx.x*blockDim.x + threadIdx.x;
  if (t >= N*8) return;
  int node = t >> 3, h = t & 7;
  const float4* xr = (const float4*)(xp + (size_t)node*128 + h*16);
  float ss = 0.f, sd = 0.f;
#pragma unroll
  for (int w = 0; w < 4; w++){
    float4 v = xr[w];
    int i = h*16 + w*4;
    ss += v.x*As[i] + v.y*As[i+1] + v.z*As[i+2] + v.w*As[i+3];
    sd += v.x*Ad[i] + v.y*Ad[i+1] + v.z*Ad[i+2] + v.w*Ad[i+3];
  }
  es[t] = ss; ed[t] = sd;
}
__global__ __launch_bounds__(256) void k_prep1(const float* __restrict__ xp,
    const float* __restrict__ As, const float* __restrict__ Ad,
    float* __restrict__ es, float* __restrict__ ed, int N){
  int gw = (blockIdx.x*256 + threadIdx.x) >> 6;
  if (gw >= N) return;
  int lane = threadIdx.x & 63;
  float2 x = *(const float2*)(xp + (size_t)gw*128 + lane*2);
  float s = x.x*As[lane*2] + x.y*As[lane*2+1];
  float d = x.x*Ad[lane*2] + x.y*Ad[lane*2+1];
#pragma unroll
  for (int o = 32; o > 0; o >>= 1){ s += __shfl_down(s, o); d += __shfl_down(d, o); }
  if (lane == 0){ es[gw] = s; ed[gw] = d; }
}

// ---------------- CSR build -----------------------------------------------------
__global__ void k_deg(const int* __restrict__ ei, int* __restrict__ deg, int E, int N){
  int t = blockIdx.x*blockDim.x + threadIdx.x;
  if (t >= E + N) return;
  int d = (t < E) ? ei[E + t] : (t - E);
  atomicAdd(&deg[d], 1);
}
__global__ void k_scan1(const int* __restrict__ deg, int* __restrict__ bsum, int N){
  __shared__ int sd[256];
  int i = blockIdx.x*256 + threadIdx.x;
  sd[threadIdx.x] = (i < N) ? deg[i] : 0;
  __syncthreads();
  for (int s = 128; s > 0; s >>= 1){
    if (threadIdx.x < s) sd[threadIdx.x] += sd[threadIdx.x + s];
    __syncthreads();
  }
  if (threadIdx.x == 0) bsum[blockIdx.x] = sd[0];
}
__global__ void k_scan2(const int* __restrict__ bsum, int* __restrict__ boff, int nb){
  if (threadIdx.x == 0 && blockIdx.x == 0){
    int acc = 0;
    for (int i = 0; i < nb; i++){ boff[i] = acc; acc += bsum[i]; }
  }
}
__global__ void k_scan3(const int* __restrict__ deg, const int* __restrict__ boff,
                        int* __restrict__ rowptr, int N){
  __shared__ int sd[256];
  int tid = threadIdx.x;
  int i = blockIdx.x*256 + tid;
  sd[tid] = (i < N) ? deg[i] : 0;
  __syncthreads();
  for (int s = 1; s < 256; s <<= 1){
    int t = (tid >= s) ? sd[tid - s] : 0;
    __syncthreads();
    sd[tid] += t;
    __syncthreads();
  }
  if (i < N) rowptr[i+1] = boff[blockIdx.x] + sd[tid];
  if (i == 0) rowptr[0] = 0;
}
__global__ void k_fill(const int* __restrict__ ei, const int* __restrict__ rowptr,
                       int* __restrict__ fil, int* __restrict__ csr, int E, int N){
  int t = blockIdx.x*blockDim.x + threadIdx.x;
  if (t >= E + N) return;
  int s, d;
  if (t < E){ s = ei[t]; d = ei[E + t]; } else { s = d = t - E; }
  int pos = rowptr[d] + atomicAdd(&fil[d], 1);
  csr[pos] = s;
}

// ---------------- GAT aggregate: one wave per dst node (in-place ok: row-local) -
template<int H, int D>
__global__ __launch_bounds__(256) void k_aggregate(
    const float* __restrict__ xp, const float* __restrict__ es, const float* __restrict__ ed,
    const int* __restrict__ rowptr, const int* __restrict__ csr,
    const float* __restrict__ bg, const float* res,
    float* out, int N)
{
  int gw = (blockIdx.x*256 + threadIdx.x) >> 6;
  if (gw >= N) return;
  int lane = threadIdx.x & 63;
  int j0 = lane*2;
  int h0 = j0 / D;
  int beg = rowptr[gw], end = rowptr[gw+1];
  float edv = ed[gw*H + h0];
  float m = -1e30f;
  for (int t = beg; t < end; t++){
    int s = csr[t];
    float e = es[s*H + h0] + edv;
    e = e > 0.f ? e : 0.2f*e;
    m = fmaxf(m, e);
  }
  float den = 0.f, a0 = 0.f, a1 = 0.f;
  for (int t = beg; t < end; t++){
    int s = csr[t];
    float e = es[s*H + h0] + edv;
    e = e > 0.f ? e : 0.2f*e;
    float w = __expf(e - m);
    den += w;
    float2 x = *(const float2*)(xp + (size_t)s*128 + j0);
    a0 += w*x.x; a1 += w*x.y;
  }
  float inv = 1.f / den;
  float o0 = a0*inv + bg[j0];
  float o1 = a1*inv + bg[j0+1];
  o0 = o0 > 0.f ? o0 : __expf(o0) - 1.f;
  o1 = o1 > 0.f ? o1 : __expf(o1) - 1.f;
  if (res){ o0 += res[(size_t)gw*128 + j0]; o1 += res[(size_t)gw*128 + j0 + 1]; }
  *(float2*)(out + (size_t)gw*128 + j0) = make_float2(o0, o1);
}

// ---------------- pooling --------------------------------------------------------
__global__ __launch_bounds__(128) void k_pool(const float* __restrict__ enh,
    const int* __restrict__ batch, float* __restrict__ Ps, float* __restrict__ Pss,
    unsigned* __restrict__ Pmx, float* __restrict__ Pcnt, int N)
{
  int tid = threadIdx.x;
  int n0 = blockIdx.x * 128;
  if (n0 >= N) return;
  int n1 = min(n0 + 128, N);
  int cur = batch[n0];
  float sum = 0.f, ssq = 0.f, mx = -1e30f, cnt = 0.f;
  auto flush = [&](int b){
    atomicAdd(&Ps[b*128 + tid], sum);
    atomicAdd(&Pss[b*128 + tid], ssq);
    atomicMax(&Pmx[b*128 + tid], f2mono(mx));
    if (tid == 0) atomicAdd(&Pcnt[b], cnt);
  };
  for (int i = n0; i < n1; i++){
    int b = batch[i];
    if (b != cur){ flush(cur); cur = b; sum = 0.f; ssq = 0.f; mx = -1e30f; cnt = 0.f; }
    float v = enh[(size_t)i*128 + tid];
    sum += v; ssq += v*v; mx = fmaxf(mx, v); cnt += 1.f;
  }
  flush(cur);
}
__global__ void k_poolfin(const float* __restrict__ Ps, const float* __restrict__ Pss,
    const unsigned* __restrict__ Pmx, const float* __restrict__ Pcnt, float* __restrict__ g)
{
  int b = blockIdx.x, j = threadIdx.x;
  float cnt = Pcnt[b];
  float c = fmaxf(cnt, 1.f);
  float mean = Ps[b*128 + j] / c;
  float var = (Pss[b*128 + j] - c*mean*mean) / fmaxf(cnt - 1.f, 1.f);
  float sd = (cnt > 1.f) ? sqrtf(fmaxf(var, 0.f)) : 0.f;
  g[b*384 + j]       = mean;
  g[b*384 + 128 + j] = mono2f(Pmx[b*128 + j]);
  g[b*384 + 256 + j] = sd;
}

// ---------------- classifier -----------------------------------------------------
__global__ void k_cls1(const float* __restrict__ g, const float* __restrict__ W,
                       const float* __restrict__ bias, float* __restrict__ out){
  __shared__ float gs[384];
  int b = blockIdx.x, t = threadIdx.x;
  for (int i = t; i < 384; i += 128) gs[i] = g[b*384 + i];
  __syncthreads();
  float acc = bias[t];
  for (int i = 0; i < 384; i++) acc += gs[i] * W[t*384 + i];
  out[b*128 + t] = fmaxf(acc, 0.f);
}
__global__ void k_cls2(const float* __restrict__ in, const float* __restrict__ W,
                       const float* __restrict__ bias, float* __restrict__ out){
  __shared__ float hs[128];
  int b = blockIdx.x, t = threadIdx.x;
  for (int i = t; i < 128; i += 64) hs[i] = in[b*128 + i];
  __syncthreads();
  float acc = bias[t];
  for (int i = 0; i < 128; i++) acc += hs[i] * W[t*128 + i];
  out[b*64 + t] = fmaxf(acc, 0.f);
}
__global__ void k_cls3(const float* __restrict__ in, const float* __restrict__ W,
                       const float* __restrict__ bias, float* __restrict__ out){
  int t = threadIdx.x;
  if (t >= 128) return;
  int b = t >> 1, o = t & 1;
  float acc = bias[o];
  for (int i = 0; i < 64; i++) acc += in[b*64 + i] * W[o*64 + i];
  out[t] = acc;                                   // f32 output, 64x2 logits
}

// ---------------- launch ---------------------------------------------------------
extern "C" void kernel_launch(void* const* d_in, const int* in_sizes, int n_in,
                              void* d_out, int out_size, void* d_ws, size_t ws_size,
                              hipStream_t stream)
{
  const float* x    = (const float*)d_in[0];
  const int*  ei    = (const int*)d_in[1];
  const int*  batch = (const int*)d_in[2];
  const float* Wi1  = (const float*)d_in[3];  const float* bi1 = (const float*)d_in[4];
  const float* Wi2  = (const float*)d_in[5];  const float* bi2 = (const float*)d_in[6];
  const float* Wg[4]= {(const float*)d_in[7],(const float*)d_in[11],(const float*)d_in[15],(const float*)d_in[19]};
  const float* As[4]= {(const float*)d_in[8],(const float*)d_in[12],(const float*)d_in[16],(const float*)d_in[20]};
  const float* Ad[4]= {(const float*)d_in[9],(const float*)d_in[13],(const float*)d_in[17],(const float*)d_in[21]};
  const float* bg[4]= {(const float*)d_in[10],(const float*)d_in[14],(const float*)d_in[18],(const float*)d_in[22]};
  const float* We1  = (const float*)d_in[23]; const float* be1 = (const float*)d_in[24];
  const float* We2  = (const float*)d_in[25]; const float* be2 = (const float*)d_in[26];
  const float* Wc1  = (const float*)d_in[27]; const float* bc1 = (const float*)d_in[28];
  const float* Wc2  = (const float*)d_in[29]; const float* bc2 = (const float*)d_in[30];
  const float* Wc3  = (const float*)d_in[31]; const float* bc3 = (const float*)d_in[32];
  float* outp = (float*)d_out;

  const int N = in_sizes[2];
  const int E = in_sizes[1] / 2;
  const int Etot = E + N;

  float* base = (float*)d_ws;
  size_t off = 0;
  auto alloc = [&](size_t elems) -> float* {
    float* p = base + off;
    off += (elems + 3) & ~(size_t)3;
    return p;
  };
  float* A   = alloc((size_t)N * 128);   // h / enh (in-place through all layers)
  float* B   = alloc((size_t)N * 128);   // gemm out / xp scratch
  float* WT  = alloc(8 * 16384);
  float* es  = alloc((size_t)N * 8);
  float* ed  = alloc((size_t)N * 8);
  int* deg   = (int*)alloc(N);           // deg+fil adjacent -> one memset
  int* fil   = (int*)alloc(N);
  int* rowptr= (int*)alloc(N + 1);
  int* bsum  = (int*)alloc(512);
  int* boff  = (int*)alloc(512);
  int* csr   = (int*)alloc(Etot);
  float* Ps  = alloc(64 * 128);          // Ps/Pss/Pmx/Pcnt adjacent -> one memset
  float* Pss = alloc(64 * 128);
  unsigned* Pmx = (unsigned*)alloc(64 * 128);
  float* Pcnt= alloc(64);
  float* g   = alloc(64 * 384);
  float* c1b = alloc(64 * 128);
  float* c2b = alloc(64 * 64);
  (void)ws_size; (void)n_in; (void)out_size;

  (void)hipMemsetAsync(deg, 0, sizeof(int) * 2 * (size_t)N, stream);
  (void)hipMemsetAsync(Ps, 0, sizeof(float) * (3 * 8192 + 64), stream);

  WPtrs wp;
  wp.w[0]=Wi1; wp.w[1]=Wi2; wp.w[2]=Wg[0]; wp.w[3]=Wg[1]; wp.w[4]=Wg[2]; wp.w[5]=Wg[3]; wp.w[6]=We1; wp.w[7]=We2;
  k_transpose_all<<<dim3(128, 8), 128, 0, stream>>>(wp, WT);

  const int gtiles = (N + 31) / 32;
  k_gemm128<1><<<gtiles, 256, 0, stream>>>(x, WT + 0*16384, bi1, nullptr, B, N);
  k_gemm128<0><<<gtiles, 256, 0, stream>>>(B, WT + 1*16384, bi2, nullptr, A, N);

  const int nb = (N + 255) / 256;
  k_deg  <<<(Etot + 255) / 256, 256, 0, stream>>>(ei, deg, E, N);
  k_scan1<<<nb, 256, 0, stream>>>(deg, bsum, N);
  k_scan2<<<1, 64, 0, stream>>>(bsum, boff, nb);
  k_scan3<<<nb, 256, 0, stream>>>(deg, boff, rowptr, N);
  k_fill <<<(Etot + 255) / 256, 256, 0, stream>>>(ei, rowptr, fil, csr, E, N);

  for (int l = 0; l < 4; l++){
    k_gemm128<0><<<gtiles, 256, 0, stream>>>(A, WT + (size_t)(2+l)*16384, nullptr, nullptr, B, N);
    if (l < 3){
      k_prep8<<<(N*8 + 255) / 256, 256, 0, stream>>>(B, As[l], Ad[l], es, ed, N);
      k_aggregate<8,16><<<(N + 3) / 4, 256, 0, stream>>>(B, es, ed, rowptr, csr, bg[l],
                                                         l > 0 ? A : nullptr, A, N);
    } else {
      k_prep1<<<(N + 3) / 4, 256, 0, stream>>>(B, As[3], Ad[3], es, ed, N);
      k_aggregate<1,128><<<(N + 3) / 4, 256, 0, stream>>>(B, es, ed, rowptr, csr, bg[3], A, A, N);
    }
  }

  // enh = A + (relu(A@We1^T+be1)@We2^T + be2), in-place into A
  k_gemm128<1><<<gtiles, 256, 0, stream>>>(A, WT + 6*16384, be1, nullptr, B, N);
  k_gemm128<0><<<gtiles, 256, 0, stream>>>(B, WT + 7*16384, be2, A, A, N);

  k_pool   <<<(N + 127) / 128, 128, 0, stream>>>(A, batch, Ps, Pss, Pmx, Pcnt, N);
  k_poolfin<<<64, 128, 0, stream>>>(Ps, Pss, Pmx, Pcnt, g);
  k_cls1   <<<64, 128, 0, stream>>>(g, Wc1, bc1, c1b);
  k_cls2   <<<64, 64, 0, stream>>>(c1b, Wc2, bc2, c2b);
  k_cls3   <<<1, 128, 0, stream>>>(c2b, Wc3, bc3, outp);
}

// Round 6
// 732.874 us; speedup vs baseline: 1.3907x; 1.3907x over previous
//
#include <hip/hip_runtime.h>
#include <hip/hip_fp16.h>
#include <cstddef>

__device__ __forceinline__ unsigned f2mono(float f){
  unsigned u = __float_as_uint(f);
  return (u & 0x80000000u) ? ~u : (u | 0x80000000u);
}
__device__ __forceinline__ float mono2f(unsigned u){
  return (u & 0x80000000u) ? __uint_as_float(u & 0x7fffffffu) : __uint_as_float(~u);
}

// ---------------- weight transpose: Wt[k][j] = W[j][k], 128x128 f32 ------------
struct WPtrs { const float* w[8]; };
__global__ void k_transpose_all(WPtrs p, float* __restrict__ WT){
  int wi = blockIdx.y;
  const float* W = p.w[wi];
  float* Wt = WT + (size_t)wi * 16384;
  int j = blockIdx.x, k = threadIdx.x;
  Wt[k*128 + j] = W[j*128 + k];
}

// ---------------- GEMM 128: out[r][j] = act(sum_k in[r][k]*W[j][k] + b[j]) (+res)
// TOUT = float (normal) or __half (xp staging for the gather-heavy aggregate)
template<int ACT, typename TOUT>   // ACT: 0 none, 1 relu
__global__ __launch_bounds__(256) void k_gemm128(
    const float* __restrict__ in, const float* __restrict__ Wt,
    const float* __restrict__ bias, const float* __restrict__ res,
    TOUT* __restrict__ out, int n)
{
  __shared__ float in_s[32][132];
  const int tid = threadIdx.x;
  const int r0 = blockIdx.x * 32;
  {
    int r = tid >> 3, kk = (tid & 7) * 16;
    int gr = r0 + r;
    float4* dst = (float4*)&in_s[r][kk];
    if (gr < n){
      const float4* q = (const float4*)(in + (size_t)gr*128 + kk);
#pragma unroll
      for (int w = 0; w < 4; w++) dst[w] = q[w];
    } else {
#pragma unroll
      for (int w = 0; w < 4; w++) dst[w] = make_float4(0.f,0.f,0.f,0.f);
    }
  }
  __syncthreads();
  const int rg = tid >> 5, cg = tid & 31, j0 = cg*4;
  float acc[4][4] = {};
  for (int k = 0; k < 128; k += 4){
    float4 w0 = *(const float4*)(Wt + (size_t)(k+0)*128 + j0);
    float4 w1 = *(const float4*)(Wt + (size_t)(k+1)*128 + j0);
    float4 w2 = *(const float4*)(Wt + (size_t)(k+2)*128 + j0);
    float4 w3 = *(const float4*)(Wt + (size_t)(k+3)*128 + j0);
#pragma unroll
    for (int i = 0; i < 4; i++){
      float4 a = *(const float4*)&in_s[rg*4+i][k];
      acc[i][0] += a.x*w0.x; acc[i][1] += a.x*w0.y; acc[i][2] += a.x*w0.z; acc[i][3] += a.x*w0.w;
      acc[i][0] += a.y*w1.x; acc[i][1] += a.y*w1.y; acc[i][2] += a.y*w1.z; acc[i][3] += a.y*w1.w;
      acc[i][0] += a.z*w2.x; acc[i][1] += a.z*w2.y; acc[i][2] += a.z*w2.z; acc[i][3] += a.z*w2.w;
      acc[i][0] += a.w*w3.x; acc[i][1] += a.w*w3.y; acc[i][2] += a.w*w3.z; acc[i][3] += a.w*w3.w;
    }
  }
  float bv[4] = {0.f,0.f,0.f,0.f};
  if (bias){ bv[0]=bias[j0]; bv[1]=bias[j0+1]; bv[2]=bias[j0+2]; bv[3]=bias[j0+3]; }
#pragma unroll
  for (int i = 0; i < 4; i++){
    int gr = r0 + rg*4 + i;
    if (gr >= n) continue;
    float4 o;
    o.x = acc[i][0]+bv[0]; o.y = acc[i][1]+bv[1]; o.z = acc[i][2]+bv[2]; o.w = acc[i][3]+bv[3];
    if (ACT == 1){ o.x=fmaxf(o.x,0.f); o.y=fmaxf(o.y,0.f); o.z=fmaxf(o.z,0.f); o.w=fmaxf(o.w,0.f); }
    if (res){
      float4 rv = *(const float4*)(res + (size_t)gr*128 + j0);
      o.x+=rv.x; o.y+=rv.y; o.z+=rv.z; o.w+=rv.w;
    }
    if constexpr (__is_same(TOUT, float)){
      *(float4*)(out + (size_t)gr*128 + j0) = o;
    } else {
      union { __half2 h2[2]; float2 f2; } u;
      u.h2[0] = __floats2half2_rn(o.x, o.y);
      u.h2[1] = __floats2half2_rn(o.z, o.w);
      *(float2*)((__half*)out + (size_t)gr*128 + j0) = u.f2;
    }
  }
}

// ---------------- attention logits prep (xp in fp16) ---------------------------
__global__ void k_prep8(const __half* __restrict__ xp, const float* __restrict__ As,
                        const float* __restrict__ Ad, float* __restrict__ es,
                        float* __restrict__ ed, int N){
  int t = blockIdx.x*blockDim.x + threadIdx.x;
  if (t >= N*8) return;
  int node = t >> 3, h = t & 7;
  const __half2* xr = (const __half2*)(xp + (size_t)node*128 + h*16);
  float ss = 0.f, sd = 0.f;
#pragma unroll
  for (int w = 0; w < 8; w++){
    float2 v = __half22float2(xr[w]);
    int i = h*16 + w*2;
    ss += v.x*As[i] + v.y*As[i+1];
    sd += v.x*Ad[i] + v.y*Ad[i+1];
  }
  es[t] = ss; ed[t] = sd;
}
__global__ __launch_bounds__(256) void k_prep1(const __half* __restrict__ xp,
    const float* __restrict__ As, const float* __restrict__ Ad,
    float* __restrict__ es, float* __restrict__ ed, int N){
  int gw = (blockIdx.x*256 + threadIdx.x) >> 6;
  if (gw >= N) return;
  int lane = threadIdx.x & 63;
  float2 x = __half22float2(*(const __half2*)(xp + (size_t)gw*128 + lane*2));
  float s = x.x*As[lane*2] + x.y*As[lane*2+1];
  float d = x.x*Ad[lane*2] + x.y*Ad[lane*2+1];
#pragma unroll
  for (int o = 32; o > 0; o >>= 1){ s += __shfl_down(s, o); d += __shfl_down(d, o); }
  if (lane == 0){ es[gw] = s; ed[gw] = d; }
}

// ---------------- CSR build -----------------------------------------------------
__global__ void k_deg(const int* __restrict__ ei, int* __restrict__ deg, int E, int N){
  int t = blockIdx.x*blockDim.x + threadIdx.x;
  if (t >= E + N) return;
  int d = (t < E) ? ei[E + t] : (t - E);
  atomicAdd(&deg[d], 1);
}
__global__ void k_scan1(const int* __restrict__ deg, int* __restrict__ bsum, int N){
  __shared__ int sd[256];
  int i = blockIdx.x*256 + threadIdx.x;
  sd[threadIdx.x] = (i < N) ? deg[i] : 0;
  __syncthreads();
  for (int s = 128; s > 0; s >>= 1){
    if (threadIdx.x < s) sd[threadIdx.x] += sd[threadIdx.x + s];
    __syncthreads();
  }
  if (threadIdx.x == 0) bsum[blockIdx.x] = sd[0];
}
__global__ void k_scan2(const int* __restrict__ bsum, int* __restrict__ boff, int nb){
  if (threadIdx.x == 0 && blockIdx.x == 0){
    int acc = 0;
    for (int i = 0; i < nb; i++){ boff[i] = acc; acc += bsum[i]; }
  }
}
__global__ void k_scan3(const int* __restrict__ deg, const int* __restrict__ boff,
                        int* __restrict__ rowptr, int N){
  __shared__ int sd[256];
  int tid = threadIdx.x;
  int i = blockIdx.x*256 + tid;
  sd[tid] = (i < N) ? deg[i] : 0;
  __syncthreads();
  for (int s = 1; s < 256; s <<= 1){
    int t = (tid >= s) ? sd[tid - s] : 0;
    __syncthreads();
    sd[tid] += t;
    __syncthreads();
  }
  if (i < N) rowptr[i+1] = boff[blockIdx.x] + sd[tid];
  if (i == 0) rowptr[0] = 0;
}
__global__ void k_fill(const int* __restrict__ ei, const int* __restrict__ rowptr,
                       int* __restrict__ fil, int* __restrict__ csr, int E, int N){
  int t = blockIdx.x*blockDim.x + threadIdx.x;
  if (t >= E + N) return;
  int s, d;
  if (t < E){ s = ei[t]; d = ei[E + t]; } else { s = d = t - E; }
  int pos = rowptr[d] + atomicAdd(&fil[d], 1);
  csr[pos] = s;
}

// ---------------- GAT aggregate: online softmax, single pass, fp16 xp gathers ---
// one wave per dst node; batches of 4 edges for memory-level parallelism
template<int H, int D>
__global__ __launch_bounds__(256) void k_aggregate(
    const __half* __restrict__ xp, const float* __restrict__ es, const float* __restrict__ ed,
    const int* __restrict__ rowptr, const int* __restrict__ csr,
    const float* __restrict__ bg, const float* res,
    float* out, int N)
{
  int gw = (blockIdx.x*256 + threadIdx.x) >> 6;
  if (gw >= N) return;
  int lane = threadIdx.x & 63;
  int j0 = lane*2;
  int h0 = j0 / D;
  int beg = rowptr[gw], end = rowptr[gw+1];
  float edv = ed[gw*H + h0];
  float m = -1e30f, den = 0.f, a0 = 0.f, a1 = 0.f;
  int t = beg;
  for (; t + 4 <= end; t += 4){
    int s0 = csr[t], s1 = csr[t+1], s2 = csr[t+2], s3 = csr[t+3];
    float e0 = es[s0*H + h0] + edv; e0 = e0 > 0.f ? e0 : 0.2f*e0;
    float e1 = es[s1*H + h0] + edv; e1 = e1 > 0.f ? e1 : 0.2f*e1;
    float e2 = es[s2*H + h0] + edv; e2 = e2 > 0.f ? e2 : 0.2f*e2;
    float e3 = es[s3*H + h0] + edv; e3 = e3 > 0.f ? e3 : 0.2f*e3;
    __half2 q0 = *(const __half2*)(xp + (size_t)s0*128 + j0);
    __half2 q1 = *(const __half2*)(xp + (size_t)s1*128 + j0);
    __half2 q2 = *(const __half2*)(xp + (size_t)s2*128 + j0);
    __half2 q3 = *(const __half2*)(xp + (size_t)s3*128 + j0);
    float mn = fmaxf(m, fmaxf(fmaxf(e0, e1), fmaxf(e2, e3)));
    float sc = __expf(m - mn);
    float w0 = __expf(e0 - mn), w1 = __expf(e1 - mn);
    float w2 = __expf(e2 - mn), w3 = __expf(e3 - mn);
    float2 f0 = __half22float2(q0), f1 = __half22float2(q1);
    float2 f2 = __half22float2(q2), f3 = __half22float2(q3);
    den = den*sc + (w0 + w1) + (w2 + w3);
    a0  = a0*sc + w0*f0.x + w1*f1.x + w2*f2.x + w3*f3.x;
    a1  = a1*sc + w0*f0.y + w1*f1.y + w2*f2.y + w3*f3.y;
    m = mn;
  }
  for (; t < end; t++){
    int s = csr[t];
    float e = es[s*H + h0] + edv;
    e = e > 0.f ? e : 0.2f*e;
    float mn = fmaxf(m, e);
    float sc = __expf(m - mn);
    float w = __expf(e - mn);
    float2 f = __half22float2(*(const __half2*)(xp + (size_t)s*128 + j0));
    den = den*sc + w;
    a0  = a0*sc + w*f.x;
    a1  = a1*sc + w*f.y;
    m = mn;
  }
  float inv = 1.f / den;
  float o0 = a0*inv + bg[j0];
  float o1 = a1*inv + bg[j0+1];
  o0 = o0 > 0.f ? o0 : __expf(o0) - 1.f;
  o1 = o1 > 0.f ? o1 : __expf(o1) - 1.f;
  if (res){ o0 += res[(size_t)gw*128 + j0]; o1 += res[(size_t)gw*128 + j0 + 1]; }
  *(float2*)(out + (size_t)gw*128 + j0) = make_float2(o0, o1);
}

// ---------------- pooling --------------------------------------------------------
__global__ __launch_bounds__(128) void k_pool(const float* __restrict__ enh,
    const int* __restrict__ batch, float* __restrict__ Ps, float* __restrict__ Pss,
    unsigned* __restrict__ Pmx, float* __restrict__ Pcnt, int N)
{
  int tid = threadIdx.x;
  int n0 = blockIdx.x * 128;
  if (n0 >= N) return;
  int n1 = min(n0 + 128, N);
  int cur = batch[n0];
  float sum = 0.f, ssq = 0.f, mx = -1e30f, cnt = 0.f;
  auto flush = [&](int b){
    atomicAdd(&Ps[b*128 + tid], sum);
    atomicAdd(&Pss[b*128 + tid], ssq);
    atomicMax(&Pmx[b*128 + tid], f2mono(mx));
    if (tid == 0) atomicAdd(&Pcnt[b], cnt);
  };
  for (int i = n0; i < n1; i++){
    int b = batch[i];
    if (b != cur){ flush(cur); cur = b; sum = 0.f; ssq = 0.f; mx = -1e30f; cnt = 0.f; }
    float v = enh[(size_t)i*128 + tid];
    sum += v; ssq += v*v; mx = fmaxf(mx, v); cnt += 1.f;
  }
  flush(cur);
}
__global__ void k_poolfin(const float* __restrict__ Ps, const float* __restrict__ Pss,
    const unsigned* __restrict__ Pmx, const float* __restrict__ Pcnt, float* __restrict__ g)
{
  int b = blockIdx.x, j = threadIdx.x;
  float cnt = Pcnt[b];
  float c = fmaxf(cnt, 1.f);
  float mean = Ps[b*128 + j] / c;
  float var = (Pss[b*128 + j] - c*mean*mean) / fmaxf(cnt - 1.f, 1.f);
  float sd = (cnt > 1.f) ? sqrtf(fmaxf(var, 0.f)) : 0.f;
  g[b*384 + j]       = mean;
  g[b*384 + 128 + j] = mono2f(Pmx[b*128 + j]);
  g[b*384 + 256 + j] = sd;
}

// ---------------- classifier -----------------------------------------------------
__global__ void k_cls1(const float* __restrict__ g, const float* __restrict__ W,
                       const float* __restrict__ bias, float* __restrict__ out){
  __shared__ float gs[384];
  int b = blockIdx.x, t = threadIdx.x;
  for (int i = t; i < 384; i += 128) gs[i] = g[b*384 + i];
  __syncthreads();
  float acc = bias[t];
  for (int i = 0; i < 384; i++) acc += gs[i] * W[t*384 + i];
  out[b*128 + t] = fmaxf(acc, 0.f);
}
__global__ void k_cls2(const float* __restrict__ in, const float* __restrict__ W,
                       const float* __restrict__ bias, float* __restrict__ out){
  __shared__ float hs[128];
  int b = blockIdx.x, t = threadIdx.x;
  for (int i = t; i < 128; i += 64) hs[i] = in[b*128 + i];
  __syncthreads();
  float acc = bias[t];
  for (int i = 0; i < 128; i++) acc += hs[i] * W[t*128 + i];
  out[b*64 + t] = fmaxf(acc, 0.f);
}
__global__ void k_cls3(const float* __restrict__ in, const float* __restrict__ W,
                       const float* __restrict__ bias, float* __restrict__ out){
  int t = threadIdx.x;
  if (t >= 128) return;
  int b = t >> 1, o = t & 1;
  float acc = bias[o];
  for (int i = 0; i < 64; i++) acc += in[b*64 + i] * W[o*64 + i];
  out[t] = acc;
}

// ---------------- launch ---------------------------------------------------------
extern "C" void kernel_launch(void* const* d_in, const int* in_sizes, int n_in,
                              void* d_out, int out_size, void* d_ws, size_t ws_size,
                              hipStream_t stream)
{
  const float* x    = (const float*)d_in[0];
  const int*  ei    = (const int*)d_in[1];
  const int*  batch = (const int*)d_in[2];
  const float* Wi1  = (const float*)d_in[3];  const float* bi1 = (const float*)d_in[4];
  const float* Wi2  = (const float*)d_in[5];  const float* bi2 = (const float*)d_in[6];
  const float* Wg[4]= {(const float*)d_in[7],(const float*)d_in[11],(const float*)d_in[15],(const float*)d_in[19]};
  const float* As[4]= {(const float*)d_in[8],(const float*)d_in[12],(const float*)d_in[16],(const float*)d_in[20]};
  const float* Ad[4]= {(const float*)d_in[9],(const float*)d_in[13],(const float*)d_in[17],(const float*)d_in[21]};
  const float* bg[4]= {(const float*)d_in[10],(const float*)d_in[14],(const float*)d_in[18],(const float*)d_in[22]};
  const float* We1  = (const float*)d_in[23]; const float* be1 = (const float*)d_in[24];
  const float* We2  = (const float*)d_in[25]; const float* be2 = (const float*)d_in[26];
  const float* Wc1  = (const float*)d_in[27]; const float* bc1 = (const float*)d_in[28];
  const float* Wc2  = (const float*)d_in[29]; const float* bc2 = (const float*)d_in[30];
  const float* Wc3  = (const float*)d_in[31]; const float* bc3 = (const float*)d_in[32];
  float* outp = (float*)d_out;

  const int N = in_sizes[2];
  const int E = in_sizes[1] / 2;
  const int Etot = E + N;

  float* base = (float*)d_ws;
  size_t off = 0;
  auto alloc = [&](size_t elems) -> float* {
    float* p = base + off;
    off += (elems + 3) & ~(size_t)3;
    return p;
  };
  float* A    = alloc((size_t)N * 128);   // h / enh (in-place through all layers)
  float* B    = alloc((size_t)N * 128);   // f32 gemm scratch (proj, enh mid)
  __half* Xh  = (__half*)alloc((size_t)N * 64);   // fp16 xp staging (N*128 halves)
  float* WT   = alloc(8 * 16384);
  float* es   = alloc((size_t)N * 8);
  float* ed   = alloc((size_t)N * 8);
  int* deg    = (int*)alloc(N);           // deg+fil adjacent -> one memset
  int* fil    = (int*)alloc(N);
  int* rowptr = (int*)alloc(N + 1);
  int* bsum   = (int*)alloc(512);
  int* boff   = (int*)alloc(512);
  int* csr    = (int*)alloc(Etot);
  float* Ps   = alloc(64 * 128);          // Ps/Pss/Pmx/Pcnt adjacent -> one memset
  float* Pss  = alloc(64 * 128);
  unsigned* Pmx = (unsigned*)alloc(64 * 128);
  float* Pcnt = alloc(64);
  float* g    = alloc(64 * 384);
  float* c1b  = alloc(64 * 128);
  float* c2b  = alloc(64 * 64);
  (void)ws_size; (void)n_in; (void)out_size;

  (void)hipMemsetAsync(deg, 0, sizeof(int) * 2 * (size_t)N, stream);
  (void)hipMemsetAsync(Ps, 0, sizeof(float) * (3 * 8192 + 64), stream);

  WPtrs wp;
  wp.w[0]=Wi1; wp.w[1]=Wi2; wp.w[2]=Wg[0]; wp.w[3]=Wg[1]; wp.w[4]=Wg[2]; wp.w[5]=Wg[3]; wp.w[6]=We1; wp.w[7]=We2;
  k_transpose_all<<<dim3(128, 8), 128, 0, stream>>>(wp, WT);

  const int gtiles = (N + 31) / 32;
  k_gemm128<1, float><<<gtiles, 256, 0, stream>>>(x, WT + 0*16384, bi1, nullptr, B, N);
  k_gemm128<0, float><<<gtiles, 256, 0, stream>>>(B, WT + 1*16384, bi2, nullptr, A, N);

  const int nb = (N + 255) / 256;
  k_deg  <<<(Etot + 255) / 256, 256, 0, stream>>>(ei, deg, E, N);
  k_scan1<<<nb, 256, 0, stream>>>(deg, bsum, N);
  k_scan2<<<1, 64, 0, stream>>>(bsum, boff, nb);
  k_scan3<<<nb, 256, 0, stream>>>(deg, boff, rowptr, N);
  k_fill <<<(Etot + 255) / 256, 256, 0, stream>>>(ei, rowptr, fil, csr, E, N);

  for (int l = 0; l < 4; l++){
    k_gemm128<0, __half><<<gtiles, 256, 0, stream>>>(A, WT + (size_t)(2+l)*16384, nullptr, nullptr, Xh, N);
    if (l < 3){
      k_prep8<<<(N*8 + 255) / 256, 256, 0, stream>>>(Xh, As[l], Ad[l], es, ed, N);
      k_aggregate<8,16><<<(N + 3) / 4, 256, 0, stream>>>(Xh, es, ed, rowptr, csr, bg[l],
                                                         l > 0 ? A : nullptr, A, N);
    } else {
      k_prep1<<<(N + 3) / 4, 256, 0, stream>>>(Xh, As[3], Ad[3], es, ed, N);
      k_aggregate<1,128><<<(N + 3) / 4, 256, 0, stream>>>(Xh, es, ed, rowptr, csr, bg[3], A, A, N);
    }
  }

  // enh = A + (relu(A@We1^T+be1)@We2^T + be2), in-place into A
  k_gemm128<1, float><<<gtiles, 256, 0, stream>>>(A, WT + 6*16384, be1, nullptr, B, N);
  k_gemm128<0, float><<<gtiles, 256, 0, stream>>>(B, WT + 7*16384, be2, A, A, N);

  k_pool   <<<(N + 127) / 128, 128, 0, stream>>>(A, batch, Ps, Pss, Pmx, Pcnt, N);
  k_poolfin<<<64, 128, 0, stream>>>(Ps, Pss, Pmx, Pcnt, g);
  k_cls1   <<<64, 128, 0, stream>>>(g, Wc1, bc1, c1b);
  k_cls2   <<<64, 64, 0, stream>>>(c1b, Wc2, bc2, c2b);
  k_cls3   <<<1, 128, 0, stream>>>(c2b, Wc3, bc3, outp);
}

// Round 7
// 634.497 us; speedup vs baseline: 1.6063x; 1.1550x over previous
//
#include <hip/hip_runtime.h>
#include <hip/hip_fp16.h>
#include <cstddef>

typedef _Float16 f16;
typedef f16 f16x8 __attribute__((ext_vector_type(8)));
typedef f16 f16x4 __attribute__((ext_vector_type(4)));
typedef float f32x4 __attribute__((ext_vector_type(4)));

__device__ __forceinline__ unsigned f2mono(float f){
  unsigned u = __float_as_uint(f);
  return (u & 0x80000000u) ? ~u : (u | 0x80000000u);
}
__device__ __forceinline__ float mono2f(unsigned u){
  return (u & 0x80000000u) ? __uint_as_float(u & 0x7fffffffu) : __uint_as_float(~u);
}

// ---------------- MFMA f16 GEMM: out[r][j] = act(sum_k in[r][k]*W[j][k]+b[j])(+res)
// D = Afrag · Bfrag^T with both frags loaded as [idx=lane&15][k=quad*8+j] (m120),
// so B-frag rows are W's original rows -> no weight transpose needed.
// Block: 256 thr = 4 waves, 64 rows (16/wave). LDS: A 64x136 f16 + W 128x136 f16.
template<int ACT, typename TOUT>   // ACT: 0 none, 1 relu
__global__ __launch_bounds__(256) void k_gemm_mfma(
    const float* __restrict__ in, const float* __restrict__ W,
    const float* __restrict__ bias, const float* __restrict__ res,
    TOUT* __restrict__ out, int n)
{
  __shared__ f16 Wl[128*136];
  __shared__ f16 Al[64*136];
  const int tid = threadIdx.x;
  const int r0 = blockIdx.x * 64;
  // stage W (128x128 f32 -> f16), coalesced: 32 thr per row
#pragma unroll
  for (int i = 0; i < 16; i++){
    int idx = tid + 256*i;
    int row = idx >> 5, c4 = (idx & 31) * 4;
    float4 v = *(const float4*)(W + row*128 + c4);
    f16x4 h = {(f16)v.x, (f16)v.y, (f16)v.z, (f16)v.w};
    *(f16x4*)&Wl[row*136 + c4] = h;
  }
  // stage A tile (64x128, guarded)
#pragma unroll
  for (int i = 0; i < 8; i++){
    int idx = tid + 256*i;
    int row = idx >> 5, c4 = (idx & 31) * 4;
    int gr = r0 + row;
    float4 v = (gr < n) ? *(const float4*)(in + (size_t)gr*128 + c4)
                        : make_float4(0.f,0.f,0.f,0.f);
    f16x4 h = {(f16)v.x, (f16)v.y, (f16)v.z, (f16)v.w};
    *(f16x4*)&Al[row*136 + c4] = h;
  }
  __syncthreads();
  const int wv = tid >> 6, lane = tid & 63;
  const int l15 = lane & 15, quad = lane >> 4;
  f32x4 acc[8] = {};
  const f16* Abase = &Al[(wv*16 + l15)*136 + quad*8];
  const f16* Bbase = &Wl[l15*136 + quad*8];
#pragma unroll
  for (int kc = 0; kc < 4; kc++){
    f16x8 a = *(const f16x8*)(Abase + kc*32);
#pragma unroll
    for (int nt = 0; nt < 8; nt++){
      f16x8 b = *(const f16x8*)(Bbase + nt*16*136 + kc*32);
      acc[nt] = __builtin_amdgcn_mfma_f32_16x16x32_f16(a, b, acc[nt], 0, 0, 0);
    }
  }
  // epilogue: D col = lane&15 (over B rows = out col), D row = quad*4+reg (A row)
#pragma unroll
  for (int nt = 0; nt < 8; nt++){
    int col = nt*16 + l15;
    float bv = bias ? bias[col] : 0.f;
#pragma unroll
    for (int reg = 0; reg < 4; reg++){
      int gr = r0 + wv*16 + quad*4 + reg;
      if (gr >= n) continue;
      float o = acc[nt][reg] + bv;
      if (ACT == 1) o = fmaxf(o, 0.f);
      if (res) o += res[(size_t)gr*128 + col];
      if constexpr (__is_same(TOUT, float)){
        out[(size_t)gr*128 + col] = o;
      } else {
        ((__half*)out)[(size_t)gr*128 + col] = __float2half(o);
      }
    }
  }
}

// ---------------- attention logits prep (xp in fp16) ---------------------------
__global__ void k_prep8(const __half* __restrict__ xp, const float* __restrict__ As,
                        const float* __restrict__ Ad, float* __restrict__ es,
                        float* __restrict__ ed, int N){
  int t = blockIdx.x*blockDim.x + threadIdx.x;
  if (t >= N*8) return;
  int node = t >> 3, h = t & 7;
  const __half2* xr = (const __half2*)(xp + (size_t)node*128 + h*16);
  float ss = 0.f, sd = 0.f;
#pragma unroll
  for (int w = 0; w < 8; w++){
    float2 v = __half22float2(xr[w]);
    int i = h*16 + w*2;
    ss += v.x*As[i] + v.y*As[i+1];
    sd += v.x*Ad[i] + v.y*Ad[i+1];
  }
  es[t] = ss; ed[t] = sd;
}
__global__ __launch_bounds__(256) void k_prep1(const __half* __restrict__ xp,
    const float* __restrict__ As, const float* __restrict__ Ad,
    float* __restrict__ es, float* __restrict__ ed, int N){
  int gw = (blockIdx.x*256 + threadIdx.x) >> 6;
  if (gw >= N) return;
  int lane = threadIdx.x & 63;
  float2 x = __half22float2(*(const __half2*)(xp + (size_t)gw*128 + lane*2));
  float s = x.x*As[lane*2] + x.y*As[lane*2+1];
  float d = x.x*Ad[lane*2] + x.y*Ad[lane*2+1];
#pragma unroll
  for (int o = 32; o > 0; o >>= 1){ s += __shfl_down(s, o); d += __shfl_down(d, o); }
  if (lane == 0){ es[gw] = s; ed[gw] = d; }
}

// ---------------- CSR build -----------------------------------------------------
__global__ void k_deg(const int* __restrict__ ei, int* __restrict__ deg, int E, int N){
  int t = blockIdx.x*blockDim.x + threadIdx.x;
  if (t >= E + N) return;
  int d = (t < E) ? ei[E + t] : (t - E);
  atomicAdd(&deg[d], 1);
}
__global__ void k_scan1(const int* __restrict__ deg, int* __restrict__ bsum, int N){
  __shared__ int sd[256];
  int i = blockIdx.x*256 + threadIdx.x;
  sd[threadIdx.x] = (i < N) ? deg[i] : 0;
  __syncthreads();
  for (int s = 128; s > 0; s >>= 1){
    if (threadIdx.x < s) sd[threadIdx.x] += sd[threadIdx.x + s];
    __syncthreads();
  }
  if (threadIdx.x == 0) bsum[blockIdx.x] = sd[0];
}
__global__ void k_scan2(const int* __restrict__ bsum, int* __restrict__ boff, int nb){
  if (threadIdx.x == 0 && blockIdx.x == 0){
    int acc = 0;
    for (int i = 0; i < nb; i++){ boff[i] = acc; acc += bsum[i]; }
  }
}
__global__ void k_scan3(const int* __restrict__ deg, const int* __restrict__ boff,
                        int* __restrict__ rowptr, int N){
  __shared__ int sd[256];
  int tid = threadIdx.x;
  int i = blockIdx.x*256 + tid;
  sd[tid] = (i < N) ? deg[i] : 0;
  __syncthreads();
  for (int s = 1; s < 256; s <<= 1){
    int t = (tid >= s) ? sd[tid - s] : 0;
    __syncthreads();
    sd[tid] += t;
    __syncthreads();
  }
  if (i < N) rowptr[i+1] = boff[blockIdx.x] + sd[tid];
  if (i == 0) rowptr[0] = 0;
}
__global__ void k_fill(const int* __restrict__ ei, const int* __restrict__ rowptr,
                       int* __restrict__ fil, int* __restrict__ csr, int E, int N){
  int t = blockIdx.x*blockDim.x + threadIdx.x;
  if (t >= E + N) return;
  int s, d;
  if (t < E){ s = ei[t]; d = ei[E + t]; } else { s = d = t - E; }
  int pos = rowptr[d] + atomicAdd(&fil[d], 1);
  csr[pos] = s;
}

// ---------------- GAT aggregate: online softmax, single pass, fp16 xp gathers ---
template<int H, int D>
__global__ __launch_bounds__(256) void k_aggregate(
    const __half* __restrict__ xp, const float* __restrict__ es, const float* __restrict__ ed,
    const int* __restrict__ rowptr, const int* __restrict__ csr,
    const float* __restrict__ bg, const float* res,
    float* out, int N)
{
  int gw = (blockIdx.x*256 + threadIdx.x) >> 6;
  if (gw >= N) return;
  int lane = threadIdx.x & 63;
  int j0 = lane*2;
  int h0 = j0 / D;
  int beg = rowptr[gw], end = rowptr[gw+1];
  float edv = ed[gw*H + h0];
  float m = -1e30f, den = 0.f, a0 = 0.f, a1 = 0.f;
  int t = beg;
  for (; t + 4 <= end; t += 4){
    int s0 = csr[t], s1 = csr[t+1], s2 = csr[t+2], s3 = csr[t+3];
    float e0 = es[s0*H + h0] + edv; e0 = e0 > 0.f ? e0 : 0.2f*e0;
    float e1 = es[s1*H + h0] + edv; e1 = e1 > 0.f ? e1 : 0.2f*e1;
    float e2 = es[s2*H + h0] + edv; e2 = e2 > 0.f ? e2 : 0.2f*e2;
    float e3 = es[s3*H + h0] + edv; e3 = e3 > 0.f ? e3 : 0.2f*e3;
    __half2 q0 = *(const __half2*)(xp + (size_t)s0*128 + j0);
    __half2 q1 = *(const __half2*)(xp + (size_t)s1*128 + j0);
    __half2 q2 = *(const __half2*)(xp + (size_t)s2*128 + j0);
    __half2 q3 = *(const __half2*)(xp + (size_t)s3*128 + j0);
    float mn = fmaxf(m, fmaxf(fmaxf(e0, e1), fmaxf(e2, e3)));
    float sc = __expf(m - mn);
    float w0 = __expf(e0 - mn), w1 = __expf(e1 - mn);
    float w2 = __expf(e2 - mn), w3 = __expf(e3 - mn);
    float2 f0 = __half22float2(q0), f1 = __half22float2(q1);
    float2 f2 = __half22float2(q2), f3 = __half22float2(q3);
    den = den*sc + (w0 + w1) + (w2 + w3);
    a0  = a0*sc + w0*f0.x + w1*f1.x + w2*f2.x + w3*f3.x;
    a1  = a1*sc + w0*f0.y + w1*f1.y + w2*f2.y + w3*f3.y;
    m = mn;
  }
  for (; t < end; t++){
    int s = csr[t];
    float e = es[s*H + h0] + edv;
    e = e > 0.f ? e : 0.2f*e;
    float mn = fmaxf(m, e);
    float sc = __expf(m - mn);
    float w = __expf(e - mn);
    float2 f = __half22float2(*(const __half2*)(xp + (size_t)s*128 + j0));
    den = den*sc + w;
    a0  = a0*sc + w*f.x;
    a1  = a1*sc + w*f.y;
    m = mn;
  }
  float inv = 1.f / den;
  float o0 = a0*inv + bg[j0];
  float o1 = a1*inv + bg[j0+1];
  o0 = o0 > 0.f ? o0 : __expf(o0) - 1.f;
  o1 = o1 > 0.f ? o1 : __expf(o1) - 1.f;
  if (res){ o0 += res[(size_t)gw*128 + j0]; o1 += res[(size_t)gw*128 + j0 + 1]; }
  *(float2*)(out + (size_t)gw*128 + j0) = make_float2(o0, o1);
}

// ---------------- pooling --------------------------------------------------------
__global__ __launch_bounds__(128) void k_pool(const float* __restrict__ enh,
    const int* __restrict__ batch, float* __restrict__ Ps, float* __restrict__ Pss,
    unsigned* __restrict__ Pmx, float* __restrict__ Pcnt, int N)
{
  int tid = threadIdx.x;
  int n0 = blockIdx.x * 128;
  if (n0 >= N) return;
  int n1 = min(n0 + 128, N);
  int cur = batch[n0];
  float sum = 0.f, ssq = 0.f, mx = -1e30f, cnt = 0.f;
  auto flush = [&](int b){
    atomicAdd(&Ps[b*128 + tid], sum);
    atomicAdd(&Pss[b*128 + tid], ssq);
    atomicMax(&Pmx[b*128 + tid], f2mono(mx));
    if (tid == 0) atomicAdd(&Pcnt[b], cnt);
  };
  for (int i = n0; i < n1; i++){
    int b = batch[i];
    if (b != cur){ flush(cur); cur = b; sum = 0.f; ssq = 0.f; mx = -1e30f; cnt = 0.f; }
    float v = enh[(size_t)i*128 + tid];
    sum += v; ssq += v*v; mx = fmaxf(mx, v); cnt += 1.f;
  }
  flush(cur);
}
__global__ void k_poolfin(const float* __restrict__ Ps, const float* __restrict__ Pss,
    const unsigned* __restrict__ Pmx, const float* __restrict__ Pcnt, float* __restrict__ g)
{
  int b = blockIdx.x, j = threadIdx.x;
  float cnt = Pcnt[b];
  float c = fmaxf(cnt, 1.f);
  float mean = Ps[b*128 + j] / c;
  float var = (Pss[b*128 + j] - c*mean*mean) / fmaxf(cnt - 1.f, 1.f);
  float sd = (cnt > 1.f) ? sqrtf(fmaxf(var, 0.f)) : 0.f;
  g[b*384 + j]       = mean;
  g[b*384 + 128 + j] = mono2f(Pmx[b*128 + j]);
  g[b*384 + 256 + j] = sd;
}

// ---------------- classifier -----------------------------------------------------
__global__ void k_cls1(const float* __restrict__ g, const float* __restrict__ W,
                       const float* __restrict__ bias, float* __restrict__ out){
  __shared__ float gs[384];
  int b = blockIdx.x, t = threadIdx.x;
  for (int i = t; i < 384; i += 128) gs[i] = g[b*384 + i];
  __syncthreads();
  float acc = bias[t];
  for (int i = 0; i < 384; i++) acc += gs[i] * W[t*384 + i];
  out[b*128 + t] = fmaxf(acc, 0.f);
}
__global__ void k_cls2(const float* __restrict__ in, const float* __restrict__ W,
                       const float* __restrict__ bias, float* __restrict__ out){
  __shared__ float hs[128];
  int b = blockIdx.x, t = threadIdx.x;
  for (int i = t; i < 128; i += 64) hs[i] = in[b*128 + i];
  __syncthreads();
  float acc = bias[t];
  for (int i = 0; i < 128; i++) acc += hs[i] * W[t*128 + i];
  out[b*64 + t] = fmaxf(acc, 0.f);
}
__global__ void k_cls3(const float* __restrict__ in, const float* __restrict__ W,
                       const float* __restrict__ bias, float* __restrict__ out){
  int t = threadIdx.x;
  if (t >= 128) return;
  int b = t >> 1, o = t & 1;
  float acc = bias[o];
  for (int i = 0; i < 64; i++) acc += in[b*64 + i] * W[o*64 + i];
  out[t] = acc;
}

// ---------------- launch ---------------------------------------------------------
extern "C" void kernel_launch(void* const* d_in, const int* in_sizes, int n_in,
                              void* d_out, int out_size, void* d_ws, size_t ws_size,
                              hipStream_t stream)
{
  const float* x    = (const float*)d_in[0];
  const int*  ei    = (const int*)d_in[1];
  const int*  batch = (const int*)d_in[2];
  const float* Wi1  = (const float*)d_in[3];  const float* bi1 = (const float*)d_in[4];
  const float* Wi2  = (const float*)d_in[5];  const float* bi2 = (const float*)d_in[6];
  const float* Wg[4]= {(const float*)d_in[7],(const float*)d_in[11],(const float*)d_in[15],(const float*)d_in[19]};
  const float* As[4]= {(const float*)d_in[8],(const float*)d_in[12],(const float*)d_in[16],(const float*)d_in[20]};
  const float* Ad[4]= {(const float*)d_in[9],(const float*)d_in[13],(const float*)d_in[17],(const float*)d_in[21]};
  const float* bg[4]= {(const float*)d_in[10],(const float*)d_in[14],(const float*)d_in[18],(const float*)d_in[22]};
  const float* We1  = (const float*)d_in[23]; const float* be1 = (const float*)d_in[24];
  const float* We2  = (const float*)d_in[25]; const float* be2 = (const float*)d_in[26];
  const float* Wc1  = (const float*)d_in[27]; const float* bc1 = (const float*)d_in[28];
  const float* Wc2  = (const float*)d_in[29]; const float* bc2 = (const float*)d_in[30];
  const float* Wc3  = (const float*)d_in[31]; const float* bc3 = (const float*)d_in[32];
  float* outp = (float*)d_out;

  const int N = in_sizes[2];
  const int E = in_sizes[1] / 2;
  const int Etot = E + N;

  float* base = (float*)d_ws;
  size_t off = 0;
  auto alloc = [&](size_t elems) -> float* {
    float* p = base + off;
    off += (elems + 3) & ~(size_t)3;
    return p;
  };
  float* A    = alloc((size_t)N * 128);   // h / enh (in-place through all layers)
  float* B    = alloc((size_t)N * 128);   // f32 gemm scratch (proj, enh mid)
  __half* Xh  = (__half*)alloc((size_t)N * 64);   // fp16 xp staging
  float* es   = alloc((size_t)N * 8);
  float* ed   = alloc((size_t)N * 8);
  int* deg    = (int*)alloc(N);           // deg+fil adjacent -> one memset
  int* fil    = (int*)alloc(N);
  int* rowptr = (int*)alloc(N + 1);
  int* bsum   = (int*)alloc(512);
  int* boff   = (int*)alloc(512);
  int* csr    = (int*)alloc(Etot);
  float* Ps   = alloc(64 * 128);          // Ps/Pss/Pmx/Pcnt adjacent -> one memset
  float* Pss  = alloc(64 * 128);
  unsigned* Pmx = (unsigned*)alloc(64 * 128);
  float* Pcnt = alloc(64);
  float* g    = alloc(64 * 384);
  float* c1b  = alloc(64 * 128);
  float* c2b  = alloc(64 * 64);
  (void)ws_size; (void)n_in; (void)out_size;

  (void)hipMemsetAsync(deg, 0, sizeof(int) * 2 * (size_t)N, stream);
  (void)hipMemsetAsync(Ps, 0, sizeof(float) * (3 * 8192 + 64), stream);

  const int gtiles = (N + 63) / 64;
  k_gemm_mfma<1, float><<<gtiles, 256, 0, stream>>>(x, Wi1, bi1, nullptr, B, N);
  k_gemm_mfma<0, float><<<gtiles, 256, 0, stream>>>(B, Wi2, bi2, nullptr, A, N);

  const int nb = (N + 255) / 256;
  k_deg  <<<(Etot + 255) / 256, 256, 0, stream>>>(ei, deg, E, N);
  k_scan1<<<nb, 256, 0, stream>>>(deg, bsum, N);
  k_scan2<<<1, 64, 0, stream>>>(bsum, boff, nb);
  k_scan3<<<nb, 256, 0, stream>>>(deg, boff, rowptr, N);
  k_fill <<<(Etot + 255) / 256, 256, 0, stream>>>(ei, rowptr, fil, csr, E, N);

  for (int l = 0; l < 4; l++){
    k_gemm_mfma<0, __half><<<gtiles, 256, 0, stream>>>(A, Wg[l], nullptr, nullptr, Xh, N);
    if (l < 3){
      k_prep8<<<(N*8 + 255) / 256, 256, 0, stream>>>(Xh, As[l], Ad[l], es, ed, N);
      k_aggregate<8,16><<<(N + 3) / 4, 256, 0, stream>>>(Xh, es, ed, rowptr, csr, bg[l],
                                                         l > 0 ? A : nullptr, A, N);
    } else {
      k_prep1<<<(N + 3) / 4, 256, 0, stream>>>(Xh, As[3], Ad[3], es, ed, N);
      k_aggregate<1,128><<<(N + 3) / 4, 256, 0, stream>>>(Xh, es, ed, rowptr, csr, bg[3], A, A, N);
    }
  }

  // enh = A + (relu(A@We1^T+be1)@We2^T + be2), in-place into A
  k_gemm_mfma<1, float><<<gtiles, 256, 0, stream>>>(A, We1, be1, nullptr, B, N);
  k_gemm_mfma<0, float><<<gtiles, 256, 0, stream>>>(B, We2, be2, A, A, N);

  k_pool   <<<(N + 127) / 128, 128, 0, stream>>>(A, batch, Ps, Pss, Pmx, Pcnt, N);
  k_poolfin<<<64, 128, 0, stream>>>(Ps, Pss, Pmx, Pcnt, g);
  k_cls1   <<<64, 128, 0, stream>>>(g, Wc1, bc1, c1b);
  k_cls2   <<<64, 64, 0, stream>>>(c1b, Wc2, bc2, c2b);
  k_cls3   <<<1, 128, 0, stream>>>(c2b, Wc3, bc3, outp);
}